// Round 1
// baseline (3115.042 us; speedup 1.0000x reference)
//
#include <hip/hip_runtime.h>
#include <hip/hip_bf16.h>
#include <math.h>

#define NTOK 13824            // 24*24*24
#define MTOT 27648            // B*NTOK
#define BATCH 2
#define CIN 128
#define DMODEL 256
#define NHEAD 8
#define DK 32
#define NLAYERS 4
#define DFF 512

// ---------------------------------------------------------------------------
// Generic fp32 GEMM: C[M x N] = act(A[M x K] * B[K x N] + bias)
// BM=BN=64, BK=16, 256 threads, 4x4 per thread.
// TRANS_A: A is stored [K][M] row-major with leading dim lda (element (m,k) at
// A[k*lda+m]) -- used for the channel-major input conv.
// ACT: 0=none, 1=relu, 2=gelu(exact erf)
// All of M,N,K are multiples of the tile sizes here -> no bounds checks.
// ---------------------------------------------------------------------------
template<int ACT, bool TRANS_A>
__global__ __launch_bounds__(256) void gemm_f32(
    const float* __restrict__ A, int lda,
    const float* __restrict__ Bm, int ldb,
    const float* __restrict__ bias,
    float* __restrict__ C, int ldc,
    int K)
{
    const int m0 = blockIdx.x * 64;
    const int n0 = blockIdx.y * 64;
    __shared__ float As[16][68];
    __shared__ float Bs[16][68];
    const int t  = threadIdx.x;
    const int tm = t >> 4;      // 0..15
    const int tn = t & 15;      // 0..15
    float acc[4][4] = {};

    for (int k0 = 0; k0 < K; k0 += 16) {
        if (TRANS_A) {
            const int kk = t >> 4, mq = (t & 15) * 4;
            const float4 a4 = *(const float4*)(A + (size_t)(k0 + kk) * lda + m0 + mq);
            *(float4*)(&As[kk][mq]) = a4;
        } else {
            const int mm = t >> 2, kq = (t & 3) * 4;
            const float4 a4 = *(const float4*)(A + (size_t)(m0 + mm) * lda + k0 + kq);
            As[kq + 0][mm] = a4.x;
            As[kq + 1][mm] = a4.y;
            As[kq + 2][mm] = a4.z;
            As[kq + 3][mm] = a4.w;
        }
        {
            const int kk = t >> 4, nq = (t & 15) * 4;
            const float4 b4 = *(const float4*)(Bm + (size_t)(k0 + kk) * ldb + n0 + nq);
            *(float4*)(&Bs[kk][nq]) = b4;
        }
        __syncthreads();
        #pragma unroll
        for (int k = 0; k < 16; ++k) {
            const float4 a4 = *(const float4*)(&As[k][tm * 4]);
            const float4 b4 = *(const float4*)(&Bs[k][tn * 4]);
            const float av[4] = {a4.x, a4.y, a4.z, a4.w};
            const float bv[4] = {b4.x, b4.y, b4.z, b4.w};
            #pragma unroll
            for (int i = 0; i < 4; ++i)
                #pragma unroll
                for (int j = 0; j < 4; ++j)
                    acc[i][j] += av[i] * bv[j];
        }
        __syncthreads();
    }

    #pragma unroll
    for (int i = 0; i < 4; ++i) {
        const int m = m0 + tm * 4 + i;
        float ov[4];
        #pragma unroll
        for (int j = 0; j < 4; ++j) {
            float x = acc[i][j] + bias[n0 + tn * 4 + j];
            if (ACT == 1) x = fmaxf(x, 0.0f);
            if (ACT == 2) x = 0.5f * x * (1.0f + erff(x * 0.7071067811865476f));
            ov[j] = x;
        }
        float4 o4; o4.x = ov[0]; o4.y = ov[1]; o4.z = ov[2]; o4.w = ov[3];
        *(float4*)(C + (size_t)m * ldc + n0 + tn * 4) = o4;
    }
}

// ---------------------------------------------------------------------------
// Transpose Wx [256][128] -> [128][256]
// ---------------------------------------------------------------------------
__global__ void transpose_wx(const float* __restrict__ Wsrc, float* __restrict__ Wdst)
{
    const int c = blockIdx.x;   // 0..127
    const int o = threadIdx.x;  // 0..255
    Wdst[c * 256 + o] = Wsrc[o * 128 + c];
}

// ---------------------------------------------------------------------------
// q softmax over feature dim (dk=32 within each head), * 1/sqrt(dk)
// one block per token, thread = column
// ---------------------------------------------------------------------------
__global__ __launch_bounds__(256) void qsm_kernel(float* __restrict__ q)
{
    const int row = blockIdx.x;
    const int c   = threadIdx.x;
    float v = q[(size_t)row * 256 + c];
    float m = v;
    #pragma unroll
    for (int off = 16; off; off >>= 1) m = fmaxf(m, __shfl_xor(m, off, 32));
    const float e = __expf(v - m);
    float s = e;
    #pragma unroll
    for (int off = 16; off; off >>= 1) s += __shfl_xor(s, off, 32);
    q[(size_t)row * 256 + c] = e / s * 0.17677669529663687f; // 1/sqrt(32)
}

// ---------------------------------------------------------------------------
// k softmax over token dim: pass 1 -> per-(b, col) online max + sumexp
// grid = B*256 blocks, 256 threads
// ---------------------------------------------------------------------------
__global__ __launch_bounds__(256) void ksm_stats(
    const float* __restrict__ k, float* __restrict__ Mk, float* __restrict__ Sk)
{
    const int b = blockIdx.x >> 8;
    const int c = blockIdx.x & 255;
    const float* base = k + (size_t)b * NTOK * 256 + c;
    float m = -1e30f, s = 0.0f;
    for (int n = threadIdx.x; n < NTOK; n += 256) {
        const float v = base[(size_t)n * 256];
        if (v > m) { s = s * __expf(m - v) + 1.0f; m = v; }
        else       { s += __expf(v - m); }
    }
    __shared__ float sm[256], ss[256];
    sm[threadIdx.x] = m; ss[threadIdx.x] = s;
    __syncthreads();
    for (int off = 128; off; off >>= 1) {
        if (threadIdx.x < off) {
            const float m1 = sm[threadIdx.x], s1 = ss[threadIdx.x];
            const float m2 = sm[threadIdx.x + off], s2 = ss[threadIdx.x + off];
            const float M = fmaxf(m1, m2);
            sm[threadIdx.x] = M;
            ss[threadIdx.x] = s1 * __expf(m1 - M) + s2 * __expf(m2 - M);
        }
        __syncthreads();
    }
    if (threadIdx.x == 0) { Mk[blockIdx.x] = sm[0]; Sk[blockIdx.x] = ss[0]; }
}

// ---------------------------------------------------------------------------
// ctx[b][h][d][e] = sum_n softmax_k[n][d] * v[n][e]   (exp/S folded in)
// grid = (27 chunks of 512 tokens, 8 heads, B), 256 threads, atomic combine
// ---------------------------------------------------------------------------
__global__ __launch_bounds__(256) void ctx_kernel(
    const float* __restrict__ kbuf, const float* __restrict__ vbuf,
    const float* __restrict__ Mk, const float* __restrict__ Sk,
    float* __restrict__ ctx)
{
    const int chunk = blockIdx.x, h = blockIdx.y, b = blockIdx.z;
    const int n0 = chunk * 512;
    const int t = threadIdx.x;
    const int col = t & 31;   // e for v / feature col for k
    const int d0  = t >> 5;   // 0..7
    __shared__ float ke[32][33], ve[32][33];
    float acc[4] = {0, 0, 0, 0};
    const int gc = h * 32 + col;
    const float Mv   = Mk[b * 256 + gc];
    const float invS = 1.0f / Sk[b * 256 + gc];
    const float* kb = kbuf + (size_t)b * NTOK * 256;
    const float* vb = vbuf + (size_t)b * NTOK * 256;

    for (int sub = 0; sub < 16; ++sub) {
        const int nb = n0 + sub * 32;
        __syncthreads();
        #pragma unroll
        for (int e = 0; e < 4; ++e) {
            const int tok = d0 + e * 8;
            const size_t idx = (size_t)(nb + tok) * 256 + gc;
            ke[tok][col] = __expf(kb[idx] - Mv) * invS;
            ve[tok][col] = vb[idx];
        }
        __syncthreads();
        #pragma unroll 8
        for (int tok = 0; tok < 32; ++tok) {
            const float vv = ve[tok][col];
            #pragma unroll
            for (int j = 0; j < 4; ++j)
                acc[j] += ke[tok][d0 + 8 * j] * vv;
        }
    }
    float* cp = ctx + (size_t)(b * 8 + h) * 1024;
    #pragma unroll
    for (int j = 0; j < 4; ++j)
        atomicAdd(&cp[(d0 + 8 * j) * 32 + col], acc[j]);
}

// ---------------------------------------------------------------------------
// o[n][h*32+e] = sum_d q[n][h*32+d] * ctx[b][h][d][e]
// one block per token
// ---------------------------------------------------------------------------
__global__ __launch_bounds__(256) void ohead_kernel(
    const float* __restrict__ q, const float* __restrict__ ctx,
    float* __restrict__ outb)
{
    const int row = blockIdx.x;
    const int b = (row >= NTOK) ? 1 : 0;
    const int c = threadIdx.x;
    const int h = c >> 5, e = c & 31;
    const float* qr = q + (size_t)row * 256 + h * 32;
    const float* cp = ctx + (size_t)(b * 8 + h) * 1024 + e;
    float acc = 0.0f;
    #pragma unroll 8
    for (int d = 0; d < 32; ++d) acc += qr[d] * cp[d * 32];
    outb[(size_t)row * 256 + c] = acc;
}

// ---------------------------------------------------------------------------
// t[row] = LayerNorm(t[row] + add[row]) * g + b   (in-place on t)
// one block per token
// ---------------------------------------------------------------------------
__global__ __launch_bounds__(256) void ln_kernel(
    float* __restrict__ t, const float* __restrict__ add,
    const float* __restrict__ g, const float* __restrict__ bta)
{
    const int row = blockIdx.x;
    const int c = threadIdx.x;
    const float v = t[(size_t)row * 256 + c] + add[(size_t)row * 256 + c];
    __shared__ float red[256];
    red[c] = v; __syncthreads();
    for (int off = 128; off; off >>= 1) { if (c < off) red[c] += red[c + off]; __syncthreads(); }
    const float mu = red[0] * (1.0f / 256.0f);
    __syncthreads();
    const float dv = v - mu;
    red[c] = dv * dv; __syncthreads();
    for (int off = 128; off; off >>= 1) { if (c < off) red[c] += red[c + off]; __syncthreads(); }
    const float var = red[0] * (1.0f / 256.0f);
    const float r = rsqrtf(var + 1e-6f);
    t[(size_t)row * 256 + c] = dv * r * g[c] + bta[c];
}

// ---------------------------------------------------------------------------
// depthwise 3x3x3 conv positional embedding + residual
// one block per (b,n), thread = channel. last!=0: write volume layout to out.
// ---------------------------------------------------------------------------
__global__ __launch_bounds__(256) void posconv_kernel(
    const float* __restrict__ tin, const float* __restrict__ pw,
    const float* __restrict__ pb, float* __restrict__ outp, int last)
{
    const int n = blockIdx.x % NTOK;
    const int b = blockIdx.x / NTOK;
    const int c = threadIdx.x;
    __shared__ float w[256][29];
    #pragma unroll
    for (int j = 0; j < 27; ++j) {
        const int g = threadIdx.x + j * 256;
        w[g / 27][g % 27] = pw[g];
    }
    __syncthreads();
    const int hh = n / 576, ww = (n / 24) % 24, dd = n % 24;
    float acc = 0.0f;
    int kk = 0;
    for (int dh = -1; dh <= 1; ++dh)
        for (int dw = -1; dw <= 1; ++dw)
            for (int dz = -1; dz <= 1; ++dz, ++kk) {
                const int h2 = hh + dh, w2 = ww + dw, d2 = dd + dz;
                if ((unsigned)h2 < 24u && (unsigned)w2 < 24u && (unsigned)d2 < 24u) {
                    const int nn = (h2 * 24 + w2) * 24 + d2;
                    acc += w[c][kk] * tin[((size_t)b * NTOK + nn) * 256 + c];
                }
            }
    const float val = tin[((size_t)b * NTOK + n) * 256 + c] + acc + pb[c];
    if (last) outp[((size_t)b * 256 + c) * NTOK + n] = val;
    else      outp[((size_t)b * NTOK + n) * 256 + c] = val;
}

// ---------------------------------------------------------------------------
// launch
// ---------------------------------------------------------------------------
extern "C" void kernel_launch(void* const* d_in, const int* in_sizes, int n_in,
                              void* d_out, int out_size, void* d_ws, size_t ws_size,
                              hipStream_t stream)
{
    (void)in_sizes; (void)n_in; (void)out_size; (void)ws_size;
    const float* x     = (const float*)d_in[0];
    const float* Wx_w  = (const float*)d_in[1];
    const float* Wx_b  = (const float*)d_in[2];
    const float* Wq    = (const float*)d_in[3];
    const float* bq    = (const float*)d_in[4];
    const float* Wk    = (const float*)d_in[5];
    const float* bk    = (const float*)d_in[6];
    const float* Wv    = (const float*)d_in[7];
    const float* bv    = (const float*)d_in[8];
    const float* Wo    = (const float*)d_in[9];
    const float* bo    = (const float*)d_in[10];
    const float* ln1_g = (const float*)d_in[11];
    const float* ln1_b = (const float*)d_in[12];
    const float* ln2_g = (const float*)d_in[13];
    const float* ln2_b = (const float*)d_in[14];
    const float* fw1   = (const float*)d_in[15];
    const float* fb1   = (const float*)d_in[16];
    const float* fw2   = (const float*)d_in[17];
    const float* fb2   = (const float*)d_in[18];
    const float* pw    = (const float*)d_in[19];
    const float* pb    = (const float*)d_in[20];
    float* out = (float*)d_out;

    float* ws = (float*)d_ws;
    const size_t SZT = (size_t)MTOT * 256;          // 7077888
    float* tA   = ws;
    float* tB   = ws + SZT;
    float* qb   = ws + 2 * SZT;
    float* kb   = ws + 3 * SZT;
    float* vb   = ws + 4 * SZT;
    float* rb   = ws + 5 * SZT;
    float* hb   = kb;                                // FFN hidden overlays k+v (free then)
    float* ctx  = ws + 6 * SZT;                      // 16384
    float* Mk   = ctx + 16384;                       // 512
    float* Sk   = Mk + 512;                          // 512
    float* Wxt  = Sk + 512;                          // 32768

    // transpose Wx [256][128] -> [128][256]
    hipLaunchKernelGGL(transpose_wx, dim3(128), dim3(256), 0, stream, Wx_w, Wxt);

    // input 1x1x1 conv + relu -> tA (per batch: A^T layout GEMM)
    for (int b = 0; b < BATCH; ++b) {
        hipLaunchKernelGGL((gemm_f32<1, true>), dim3(NTOK / 64, DMODEL / 64), dim3(256), 0, stream,
                           x + (size_t)b * CIN * NTOK, NTOK, Wxt, DMODEL, Wx_b,
                           tA + (size_t)b * NTOK * 256, DMODEL, CIN);
    }

    for (int i = 0; i < NLAYERS; ++i) {
        float* tin  = (i & 1) ? tB : tA;
        float* tout = (i & 1) ? tA : tB;
        const float* wq = Wq + (size_t)i * 256 * 256;
        const float* wk = Wk + (size_t)i * 256 * 256;
        const float* wv = Wv + (size_t)i * 256 * 256;
        const float* wo = Wo + (size_t)i * 256 * 256;

        dim3 g44(MTOT / 64, DMODEL / 64);
        hipLaunchKernelGGL((gemm_f32<0, false>), g44, dim3(256), 0, stream,
                           tin, DMODEL, wq, DMODEL, bq + i * 256, qb, DMODEL, DMODEL);
        hipLaunchKernelGGL((gemm_f32<0, false>), g44, dim3(256), 0, stream,
                           tin, DMODEL, wk, DMODEL, bk + i * 256, kb, DMODEL, DMODEL);
        hipLaunchKernelGGL((gemm_f32<0, false>), g44, dim3(256), 0, stream,
                           tin, DMODEL, wv, DMODEL, bv + i * 256, vb, DMODEL, DMODEL);

        hipLaunchKernelGGL(qsm_kernel, dim3(MTOT), dim3(256), 0, stream, qb);
        hipLaunchKernelGGL(ksm_stats, dim3(BATCH * 256), dim3(256), 0, stream, kb, Mk, Sk);
        hipMemsetAsync(ctx, 0, 16384 * sizeof(float), stream);
        hipLaunchKernelGGL(ctx_kernel, dim3(27, NHEAD, BATCH), dim3(256), 0, stream,
                           kb, vb, Mk, Sk, ctx);
        hipLaunchKernelGGL(ohead_kernel, dim3(MTOT), dim3(256), 0, stream, qb, ctx, rb);

        // o @ Wo + bo -> qb (free)
        hipLaunchKernelGGL((gemm_f32<0, false>), g44, dim3(256), 0, stream,
                           rb, DMODEL, wo, DMODEL, bo + i * 256, qb, DMODEL, DMODEL);
        hipLaunchKernelGGL(ln_kernel, dim3(MTOT), dim3(256), 0, stream,
                           tin, qb, ln1_g + i * 256, ln1_b + i * 256);

        // FFN
        hipLaunchKernelGGL((gemm_f32<2, false>), dim3(MTOT / 64, DFF / 64), dim3(256), 0, stream,
                           tin, DMODEL, fw1 + (size_t)i * 256 * 512, DFF, fb1 + i * 512,
                           hb, DFF, DMODEL);
        hipLaunchKernelGGL((gemm_f32<0, false>), g44, dim3(256), 0, stream,
                           hb, DFF, fw2 + (size_t)i * 512 * 256, DMODEL, fb2 + i * 256,
                           rb, DMODEL, DFF);
        hipLaunchKernelGGL(ln_kernel, dim3(MTOT), dim3(256), 0, stream,
                           tin, rb, ln2_g + i * 256, ln2_b + i * 256);

        // depthwise 3x3x3 conv + residual
        const int last = (i == NLAYERS - 1);
        hipLaunchKernelGGL(posconv_kernel, dim3(MTOT), dim3(256), 0, stream,
                           tin, pw + (size_t)i * 256 * 27, pb + i * 256,
                           last ? out : tout, last);
    }
}

// Round 2
// 1707.704 us; speedup vs baseline: 1.8241x; 1.8241x over previous
//
#include <hip/hip_runtime.h>
#include <math.h>

#define NTOK 13824            // 24*24*24
#define MTOT 27648            // B*NTOK
#define BATCH 2
#define CIN 128
#define DMODEL 256
#define NHEAD 8
#define NLAYERS 4
#define DFF 512

typedef float f32x4 __attribute__((ext_vector_type(4)));
typedef __bf16 bf16x8 __attribute__((ext_vector_type(8)));
typedef __attribute__((address_space(1))) void gvoid;
typedef __attribute__((address_space(3))) void lvoid;

// async global->LDS, 16B per lane. LDS dest must be uniform-base + lane*16.
#define GLDS16(g, l) __builtin_amdgcn_global_load_lds((gvoid*)(g), (lvoid*)(l), 16, 0, 0)

__device__ __forceinline__ unsigned short f2bf(float f) {
    unsigned u = __float_as_uint(f);
    return (unsigned short)((u + 0x7FFFu + ((u >> 16) & 1u)) >> 16);
}
__device__ __forceinline__ float bf2f(unsigned short h) {
    return __uint_as_float(((unsigned)h) << 16);
}

// ---------------------------------------------------------------------------
// bf16 MFMA GEMM: C[M x N] = act(A[M x K](bf16) * B[K x N] + bias)
// B supplied TRANSPOSED: Bt[N][K] bf16 (rows = output cols, contiguous K).
// 128x128 tile, BK=32, 256 threads (4 waves, 2x2), each wave 64x64 via
// 4x4 grid of 16x16x32 MFMA. global_load_lds(16B) staging, m97 structure.
// ACT: 0 none, 1 relu, 2 gelu(exact). OUTM: 1 = bf16 C only, 2 = f32 + bf16.
// ---------------------------------------------------------------------------
template<int ACT, int OUTM>
__global__ __launch_bounds__(256) void gemm_bf16(
    const unsigned short* __restrict__ A, int lda,
    const unsigned short* __restrict__ Bt, int ldb,
    const float* __restrict__ bias,
    float* __restrict__ Cf, unsigned short* __restrict__ Cb,
    int ldc, int K)
{
    __shared__ __attribute__((aligned(16))) unsigned short As[4096]; // 128 x 32
    __shared__ __attribute__((aligned(16))) unsigned short Bs[4096]; // 128 x 32 (n-major)
    const int t    = threadIdx.x;
    const int lane = t & 63;
    const int wave = t >> 6;
    const int wm = wave & 1, wn = wave >> 1;
    const int m0 = blockIdx.x * 128, n0 = blockIdx.y * 128;

    // staging: chunk c covers row c>>2, k-offset (c&3)*8 (16 bytes)
    const int r0   = t >> 2;
    const int koff = (t & 3) * 8;
    const unsigned short* ga0 = A  + (size_t)(m0 + r0)      * lda + koff;
    const unsigned short* ga1 = A  + (size_t)(m0 + r0 + 64) * lda + koff;
    const unsigned short* gb0 = Bt + (size_t)(n0 + r0)      * ldb + koff;
    const unsigned short* gb1 = Bt + (size_t)(n0 + r0 + 64) * ldb + koff;
    unsigned short* la0 = As + t * 8;
    unsigned short* la1 = As + t * 8 + 2048;
    unsigned short* lb0 = Bs + t * 8;
    unsigned short* lb1 = Bs + t * 8 + 2048;

    f32x4 acc[4][4];
    #pragma unroll
    for (int i = 0; i < 4; ++i)
        #pragma unroll
        for (int j = 0; j < 4; ++j) acc[i][j] = (f32x4)0.0f;

    const int fm = lane & 15;
    const int fq = (lane >> 4) * 8;
    const int arow = (wm * 64 + fm) * 32 + fq;   // + i*512
    const int brow = (wn * 64 + fm) * 32 + fq;   // + j*512

    for (int k0 = 0; k0 < K; k0 += 32) {
        GLDS16(ga0 + k0, la0);
        GLDS16(ga1 + k0, la1);
        GLDS16(gb0 + k0, lb0);
        GLDS16(gb1 + k0, lb1);
        __syncthreads();                 // drains vmcnt(0) + barrier
        bf16x8 af[4], bg[4];
        #pragma unroll
        for (int i = 0; i < 4; ++i) af[i] = *(const bf16x8*)(As + arow + i * 512);
        #pragma unroll
        for (int j = 0; j < 4; ++j) bg[j] = *(const bf16x8*)(Bs + brow + j * 512);
        #pragma unroll
        for (int i = 0; i < 4; ++i)
            #pragma unroll
            for (int j = 0; j < 4; ++j)
                acc[i][j] = __builtin_amdgcn_mfma_f32_16x16x32_bf16(
                    af[i], bg[j], acc[i][j], 0, 0, 0);
        __syncthreads();
    }

    // epilogue: C/D layout col=lane&15 (n), row=(lane>>4)*4+reg (m)
    const int cb  = n0 + wn * 64 + fm;
    const int rbs = m0 + wm * 64 + (lane >> 4) * 4;
    #pragma unroll
    for (int j = 0; j < 4; ++j) {
        const int n = cb + j * 16;
        const float bv = bias[n];
        #pragma unroll
        for (int i = 0; i < 4; ++i) {
            #pragma unroll
            for (int r = 0; r < 4; ++r) {
                float v = acc[i][j][r] + bv;
                if (ACT == 1) v = fmaxf(v, 0.0f);
                if (ACT == 2) v = 0.5f * v * (1.0f + erff(v * 0.7071067811865476f));
                const size_t off = (size_t)(rbs + i * 16 + r) * ldc + n;
                if (OUTM == 2) Cf[off] = v;
                Cb[off] = f2bf(v);
            }
        }
    }
}

// ---------------------------------------------------------------------------
// one-shot weight conversion: transpose to [N][K] bf16 + bias concat
// ---------------------------------------------------------------------------
#define CW_QKV  786432   // 4*768*256
#define CW_O   1048576   // + 4*256*256
#define CW_1   1572864   // + 4*512*256
#define CW_2   2097152   // + 4*256*512
#define CW_X   2129920   // + 256*128
#define CW_B   2132992   // + 4*768
__global__ __launch_bounds__(256) void conv_weights(
    const float* __restrict__ Wq, const float* __restrict__ Wk,
    const float* __restrict__ Wv, const float* __restrict__ Wo,
    const float* __restrict__ fw1, const float* __restrict__ fw2,
    const float* __restrict__ Wx_w,
    const float* __restrict__ bq, const float* __restrict__ bk,
    const float* __restrict__ bv,
    unsigned short* __restrict__ wqkv_t, unsigned short* __restrict__ wo_t,
    unsigned short* __restrict__ w1_t, unsigned short* __restrict__ w2_t,
    unsigned short* __restrict__ wx_bf, float* __restrict__ bqkv)
{
    const int e = blockIdx.x * 256 + threadIdx.x;
    if (e < CW_QKV) {
        const int i = e / 196608, r = e % 196608;
        const int n = r / 256, k = r % 256;
        const float* src = (n < 256) ? Wq : (n < 512) ? Wk : Wv;
        wqkv_t[e] = f2bf(src[((size_t)i * 256 + k) * 256 + (n & 255)]);
    } else if (e < CW_O) {
        const int r = e - CW_QKV;
        const int i = r / 65536, rr = r % 65536, n = rr / 256, k = rr % 256;
        wo_t[r] = f2bf(Wo[((size_t)i * 256 + k) * 256 + n]);
    } else if (e < CW_1) {
        const int r = e - CW_O;
        const int i = r / 131072, rr = r % 131072, n = rr / 256, k = rr % 256;
        w1_t[r] = f2bf(fw1[((size_t)i * 256 + k) * 512 + n]);
    } else if (e < CW_2) {
        const int r = e - CW_1;
        const int i = r / 131072, rr = r % 131072, n = rr / 512, k = rr % 512;
        w2_t[r] = f2bf(fw2[((size_t)i * 512 + k) * 256 + n]);
    } else if (e < CW_X) {
        const int r = e - CW_2;
        wx_bf[r] = f2bf(Wx_w[r]);     // Wx_w [out][in] is already B^T layout
    } else if (e < CW_B) {
        const int r = e - CW_X;
        const int i = r / 768, j = r % 768;
        const float v = (j < 256) ? bq[i * 256 + j]
                      : (j < 512) ? bk[i * 256 + j - 256]
                                  : bv[i * 256 + j - 512];
        bqkv[r] = v;
    }
}

// x [B][CIN][NTOK] f32 -> xbf [MTOT][CIN] bf16 (token-major)
__global__ __launch_bounds__(256) void conv_x(
    const float* __restrict__ x, unsigned short* __restrict__ xbf)
{
    const int e = blockIdx.x * 256 + threadIdx.x;     // e < MTOT*128
    const int m = e >> 7, c = e & 127;
    const int b = (m >= NTOK) ? 1 : 0;
    const int n = m - b * NTOK;
    xbf[e] = f2bf(x[((size_t)b * CIN + c) * NTOK + n]);
}

// ---------------------------------------------------------------------------
// k softmax stats over tokens (per b, channel): online max + sumexp; k bf16
// ---------------------------------------------------------------------------
__global__ __launch_bounds__(256) void ksm_stats(
    const unsigned short* __restrict__ qkv, float* __restrict__ Mk, float* __restrict__ Sk)
{
    const int b = blockIdx.x >> 8;
    const int c = blockIdx.x & 255;
    const unsigned short* base = qkv + (size_t)b * NTOK * 768 + 256 + c;
    float m = -1e30f, s = 0.0f;
    for (int n = threadIdx.x; n < NTOK; n += 256) {
        const float v = bf2f(base[(size_t)n * 768]);
        if (v > m) { s = s * __expf(m - v) + 1.0f; m = v; }
        else       { s += __expf(v - m); }
    }
    __shared__ float sm[256], ss[256];
    sm[threadIdx.x] = m; ss[threadIdx.x] = s;
    __syncthreads();
    for (int off = 128; off; off >>= 1) {
        if (threadIdx.x < off) {
            const float m1 = sm[threadIdx.x], s1 = ss[threadIdx.x];
            const float m2 = sm[threadIdx.x + off], s2 = ss[threadIdx.x + off];
            const float M = fmaxf(m1, m2);
            sm[threadIdx.x] = M;
            ss[threadIdx.x] = s1 * __expf(m1 - M) + s2 * __expf(m2 - M);
        }
        __syncthreads();
    }
    if (threadIdx.x == 0) { Mk[blockIdx.x] = sm[0]; Sk[blockIdx.x] = ss[0]; }
}

// ---------------------------------------------------------------------------
// ctx[b][h][d][e] = sum_n softmaxed_k[n][d] * v[n][e]; k,v bf16 in qkv
// ---------------------------------------------------------------------------
__global__ __launch_bounds__(256) void ctx_kernel(
    const unsigned short* __restrict__ qkv,
    const float* __restrict__ Mk, const float* __restrict__ Sk,
    float* __restrict__ ctx)
{
    const int chunk = blockIdx.x, h = blockIdx.y, b = blockIdx.z;
    const int n0 = chunk * 512;
    const int t = threadIdx.x;
    const int col = t & 31;
    const int d0  = t >> 5;   // 0..7
    __shared__ float ke[32][33], ve[32][33];
    float acc[4] = {0, 0, 0, 0};
    const int gc = h * 32 + col;
    const float Mv   = Mk[b * 256 + gc];
    const float invS = 1.0f / Sk[b * 256 + gc];
    const unsigned short* kb = qkv + (size_t)b * NTOK * 768 + 256;
    const unsigned short* vb = qkv + (size_t)b * NTOK * 768 + 512;

    for (int sub = 0; sub < 16; ++sub) {
        const int nb = n0 + sub * 32;
        __syncthreads();
        #pragma unroll
        for (int e = 0; e < 4; ++e) {
            const int tok = d0 + e * 8;
            const size_t idx = (size_t)(nb + tok) * 768 + gc;
            ke[tok][col] = __expf(bf2f(kb[idx]) - Mv) * invS;
            ve[tok][col] = bf2f(vb[idx]);
        }
        __syncthreads();
        #pragma unroll 8
        for (int tok = 0; tok < 32; ++tok) {
            const float vv = ve[tok][col];
            #pragma unroll
            for (int j = 0; j < 4; ++j)
                acc[j] += ke[tok][d0 + 8 * j] * vv;
        }
    }
    float* cp = ctx + (size_t)(b * 8 + h) * 1024;
    #pragma unroll
    for (int j = 0; j < 4; ++j)
        atomicAdd(&cp[(d0 + 8 * j) * 32 + col], acc[j]);
}

// ---------------------------------------------------------------------------
// fused q-softmax (over dk=32) + o = q_sm * ctx; writes bf16 into qkv k-slot
// ---------------------------------------------------------------------------
__global__ __launch_bounds__(256) void ohead_kernel(
    unsigned short* __restrict__ qkv, const float* __restrict__ ctx)
{
    const int row = blockIdx.x;
    const int b = (row >= NTOK) ? 1 : 0;
    const int t = threadIdx.x;
    const int h = t >> 5, e = t & 31;
    const float qv = bf2f(qkv[(size_t)row * 768 + h * 32 + e]);
    float m = qv;
    #pragma unroll
    for (int off = 16; off; off >>= 1) m = fmaxf(m, __shfl_xor(m, off, 32));
    const float ex = __expf(qv - m);
    float s = ex;
    #pragma unroll
    for (int off = 16; off; off >>= 1) s += __shfl_xor(s, off, 32);
    const float qs = ex / s * 0.17677669529663687f; // 1/sqrt(32)
    const float* cp = ctx + (size_t)(b * 8 + h) * 1024 + e;
    float acc = 0.0f;
    #pragma unroll 8
    for (int d = 0; d < 32; ++d) acc += __shfl(qs, d, 32) * cp[d * 32];
    qkv[(size_t)row * 768 + 256 + t] = f2bf(acc);
}

// ---------------------------------------------------------------------------
// t = LayerNorm(t + add(bf16)); writes t f32 in place (+ optional bf16 copy)
// ---------------------------------------------------------------------------
template<int WB>
__global__ __launch_bounds__(256) void ln_kernel(
    float* __restrict__ t, const unsigned short* __restrict__ add,
    const float* __restrict__ g, const float* __restrict__ bta,
    unsigned short* __restrict__ tbf)
{
    const int row = blockIdx.x;
    const int c = threadIdx.x;
    const int lane = c & 63, wave = c >> 6;
    const size_t off = (size_t)row * 256 + c;
    const float v = t[off] + bf2f(add[off]);
    __shared__ float red[8];
    float s = v;
    #pragma unroll
    for (int o = 32; o; o >>= 1) s += __shfl_xor(s, o, 64);
    if (lane == 0) red[wave] = s;
    __syncthreads();
    const float mu = (red[0] + red[1] + red[2] + red[3]) * (1.0f / 256.0f);
    const float dv = v - mu;
    float s2 = dv * dv;
    #pragma unroll
    for (int o = 32; o; o >>= 1) s2 += __shfl_xor(s2, o, 64);
    if (lane == 0) red[wave + 4] = s2;
    __syncthreads();
    const float var = (red[4] + red[5] + red[6] + red[7]) * (1.0f / 256.0f);
    const float o = dv * rsqrtf(var + 1e-6f) * g[c] + bta[c];
    t[off] = o;
    if (WB) tbf[off] = f2bf(o);
}

// ---------------------------------------------------------------------------
// depthwise 3x3x3 conv + residual; writes token-major f32 + bf16 shadow
// ---------------------------------------------------------------------------
__global__ __launch_bounds__(256) void posconv_kernel(
    const float* __restrict__ tin, const float* __restrict__ pw,
    const float* __restrict__ pb, float* __restrict__ outp,
    unsigned short* __restrict__ tbfp)
{
    const int n = blockIdx.x % NTOK;
    const int b = blockIdx.x / NTOK;
    const int c = threadIdx.x;
    __shared__ float w[256][29];
    #pragma unroll
    for (int j = 0; j < 27; ++j) {
        const int g = threadIdx.x + j * 256;
        w[g / 27][g % 27] = pw[g];
    }
    __syncthreads();
    const int hh = n / 576, ww = (n / 24) % 24, dd = n % 24;
    float acc = 0.0f;
    int kk = 0;
    for (int dh = -1; dh <= 1; ++dh)
        for (int dw = -1; dw <= 1; ++dw)
            for (int dz = -1; dz <= 1; ++dz, ++kk) {
                const int h2 = hh + dh, w2 = ww + dw, d2 = dd + dz;
                if ((unsigned)h2 < 24u && (unsigned)w2 < 24u && (unsigned)d2 < 24u) {
                    const int nn = (h2 * 24 + w2) * 24 + d2;
                    acc += w[c][kk] * tin[((size_t)b * NTOK + nn) * 256 + c];
                }
            }
    const float val = tin[((size_t)b * NTOK + n) * 256 + c] + acc + pb[c];
    const size_t off = ((size_t)b * NTOK + n) * 256 + c;
    outp[off] = val;
    tbfp[off] = f2bf(val);
}

// ---------------------------------------------------------------------------
// final transpose: t [MTOT][256] f32 -> out [B][256][NTOK] (LDS tiled)
// ---------------------------------------------------------------------------
__global__ __launch_bounds__(256) void tr_out(
    const float* __restrict__ tin, float* __restrict__ outp)
{
    __shared__ float tile[32][33];
    const int m0 = blockIdx.x * 32;
    const int c0 = blockIdx.y * 32;
    const int t = threadIdx.x;
    const int tc = t & 31, tr = t >> 5;     // 8 row-groups
    #pragma unroll
    for (int r = 0; r < 4; ++r)
        tile[tr + r * 8][tc] = tin[(size_t)(m0 + tr + r * 8) * 256 + c0 + tc];
    __syncthreads();
    const int b = (m0 >= NTOK) ? 1 : 0;
    const int n0 = m0 - b * NTOK;
    #pragma unroll
    for (int r = 0; r < 4; ++r)
        outp[((size_t)b * 256 + c0 + tr + r * 8) * NTOK + n0 + tc] = tile[tc][tr + r * 8];
}

// ---------------------------------------------------------------------------
// launch
// ---------------------------------------------------------------------------
extern "C" void kernel_launch(void* const* d_in, const int* in_sizes, int n_in,
                              void* d_out, int out_size, void* d_ws, size_t ws_size,
                              hipStream_t stream)
{
    (void)in_sizes; (void)n_in; (void)out_size; (void)ws_size;
    const float* x     = (const float*)d_in[0];
    const float* Wx_w  = (const float*)d_in[1];
    const float* Wx_b  = (const float*)d_in[2];
    const float* Wq    = (const float*)d_in[3];
    const float* bq    = (const float*)d_in[4];
    const float* Wk    = (const float*)d_in[5];
    const float* bk    = (const float*)d_in[6];
    const float* Wv    = (const float*)d_in[7];
    const float* bv    = (const float*)d_in[8];
    const float* Wo    = (const float*)d_in[9];
    const float* bo    = (const float*)d_in[10];
    const float* ln1_g = (const float*)d_in[11];
    const float* ln1_b = (const float*)d_in[12];
    const float* ln2_g = (const float*)d_in[13];
    const float* ln2_b = (const float*)d_in[14];
    const float* fw1   = (const float*)d_in[15];
    const float* fb1   = (const float*)d_in[16];
    const float* fw2   = (const float*)d_in[17];
    const float* fb2   = (const float*)d_in[18];
    const float* pw    = (const float*)d_in[19];
    const float* pb    = (const float*)d_in[20];
    float* out = (float*)d_out;

    char* p = (char*)d_ws;
    float* tA            = (float*)p;          p += (size_t)MTOT * 256 * 4;
    float* tB            = (float*)p;          p += (size_t)MTOT * 256 * 4;
    unsigned short* tbf  = (unsigned short*)p; p += (size_t)MTOT * 256 * 2;
    unsigned short* qkv  = (unsigned short*)p; p += (size_t)MTOT * 768 * 2;
    unsigned short* hbf  = (unsigned short*)p; p += (size_t)MTOT * 512 * 2;
    unsigned short* ob   = (unsigned short*)p; p += (size_t)MTOT * 256 * 2;
    unsigned short* xbf  = (unsigned short*)p; p += (size_t)MTOT * 128 * 2;
    unsigned short* wqkv_t = (unsigned short*)p; p += (size_t)786432 * 2;
    unsigned short* wo_t   = (unsigned short*)p; p += (size_t)262144 * 2;
    unsigned short* w1_t   = (unsigned short*)p; p += (size_t)524288 * 2;
    unsigned short* w2_t   = (unsigned short*)p; p += (size_t)524288 * 2;
    unsigned short* wx_bf  = (unsigned short*)p; p += (size_t)32768 * 2;
    float* bqkv = (float*)p; p += 3072 * 4;
    float* ctx  = (float*)p; p += 16384 * 4;
    float* Mk   = (float*)p; p += 512 * 4;
    float* Sk   = (float*)p; p += 512 * 4;

    hipLaunchKernelGGL(conv_weights, dim3(8333), dim3(256), 0, stream,
                       Wq, Wk, Wv, Wo, fw1, fw2, Wx_w, bq, bk, bv,
                       wqkv_t, wo_t, w1_t, w2_t, wx_bf, bqkv);
    hipLaunchKernelGGL(conv_x, dim3(13824), dim3(256), 0, stream, x, xbf);

    // input 1x1x1 conv + relu -> tA f32 + tbf bf16
    hipLaunchKernelGGL((gemm_bf16<1, 2>), dim3(216, 2), dim3(256), 0, stream,
                       xbf, CIN, wx_bf, CIN, Wx_b, tA, tbf, 256, CIN);

    for (int i = 0; i < NLAYERS; ++i) {
        float* tin  = (i & 1) ? tB : tA;
        float* tout = (i & 1) ? tA : tB;

        // fused QKV: [M,256] x [256,768]
        hipLaunchKernelGGL((gemm_bf16<0, 1>), dim3(216, 6), dim3(256), 0, stream,
                           tbf, 256, wqkv_t + (size_t)i * 196608, 256,
                           bqkv + i * 768, nullptr, qkv, 768, 256);

        hipLaunchKernelGGL(ksm_stats, dim3(512), dim3(256), 0, stream, qkv, Mk, Sk);
        hipMemsetAsync(ctx, 0, 16384 * sizeof(float), stream);
        hipLaunchKernelGGL(ctx_kernel, dim3(27, NHEAD, BATCH), dim3(256), 0, stream,
                           qkv, Mk, Sk, ctx);
        hipLaunchKernelGGL(ohead_kernel, dim3(MTOT), dim3(256), 0, stream, qkv, ctx);

        // o @ Wo + bo -> ob (A = qkv k-slot, lda 768)
        hipLaunchKernelGGL((gemm_bf16<0, 1>), dim3(216, 2), dim3(256), 0, stream,
                           qkv + 256, 768, wo_t + (size_t)i * 65536, 256,
                           bo + i * 256, nullptr, ob, 256, 256);
        hipLaunchKernelGGL((ln_kernel<1>), dim3(MTOT), dim3(256), 0, stream,
                           tin, ob, ln1_g + i * 256, ln1_b + i * 256, tbf);

        // FFN
        hipLaunchKernelGGL((gemm_bf16<2, 1>), dim3(216, 4), dim3(256), 0, stream,
                           tbf, 256, w1_t + (size_t)i * 131072, 256,
                           fb1 + i * 512, nullptr, hbf, 512, 256);
        hipLaunchKernelGGL((gemm_bf16<0, 1>), dim3(216, 2), dim3(256), 0, stream,
                           hbf, 512, w2_t + (size_t)i * 131072, 512,
                           fb2 + i * 256, nullptr, ob, 256, 512);
        hipLaunchKernelGGL((ln_kernel<0>), dim3(MTOT), dim3(256), 0, stream,
                           tin, ob, ln2_g + i * 256, ln2_b + i * 256, nullptr);

        // depthwise conv + residual -> tout f32 + tbf bf16 (next layer input)
        hipLaunchKernelGGL(posconv_kernel, dim3(MTOT), dim3(256), 0, stream,
                           tin, pw + (size_t)i * 6912, pb + i * 256, tout, tbf);
    }

    // layer 3 wrote tA (tin alternation: A,B,A,B -> tout of i=3 is tA)
    hipLaunchKernelGGL(tr_out, dim3(MTOT / 32, 8), dim3(256), 0, stream, tA, out);
}

// Round 3
// 1245.053 us; speedup vs baseline: 2.5019x; 1.3716x over previous
//
#include <hip/hip_runtime.h>
#include <math.h>

#define NTOK 13824            // 24*24*24
#define MTOT 27648            // B*NTOK
#define BATCH 2
#define CIN 128
#define DMODEL 256
#define NHEAD 8
#define NLAYERS 4
#define DFF 512

typedef float f32x4 __attribute__((ext_vector_type(4)));
typedef __bf16 bf16x8 __attribute__((ext_vector_type(8)));
typedef __attribute__((address_space(1))) void gvoid;
typedef __attribute__((address_space(3))) void lvoid;

// async global->LDS, 16B per lane. LDS dest must be uniform-base + lane*16.
#define GLDS16(g, l) __builtin_amdgcn_global_load_lds((gvoid*)(g), (lvoid*)(l), 16, 0, 0)

__device__ __forceinline__ unsigned short f2bf(float f) {
    unsigned u = __float_as_uint(f);
    return (unsigned short)((u + 0x7FFFu + ((u >> 16) & 1u)) >> 16);
}
__device__ __forceinline__ float bf2f(unsigned short h) {
    return __uint_as_float(((unsigned)h) << 16);
}

// ---------------------------------------------------------------------------
// bf16 MFMA GEMM: C[M x N] = act(A[M x K](bf16) * B[K x N] + bias)
// B supplied TRANSPOSED: Bt[N][K] bf16. 128x128 tile, BK=32, 256 threads,
// global_load_lds(16B) staging (m97 structure).
// ACT: 0 none, 1 relu, 2 gelu(exact). OUTM: 1 = bf16 C only, 2 = f32 + bf16.
// ---------------------------------------------------------------------------
template<int ACT, int OUTM>
__global__ __launch_bounds__(256) void gemm_bf16(
    const unsigned short* __restrict__ A, int lda,
    const unsigned short* __restrict__ Bt, int ldb,
    const float* __restrict__ bias,
    float* __restrict__ Cf, unsigned short* __restrict__ Cb,
    int ldc, int K)
{
    __shared__ __attribute__((aligned(16))) unsigned short As[4096]; // 128 x 32
    __shared__ __attribute__((aligned(16))) unsigned short Bs[4096]; // 128 x 32 (n-major)
    const int t    = threadIdx.x;
    const int lane = t & 63;
    const int wave = t >> 6;
    const int wm = wave & 1, wn = wave >> 1;
    const int m0 = blockIdx.x * 128, n0 = blockIdx.y * 128;

    const int r0   = t >> 2;
    const int koff = (t & 3) * 8;
    const unsigned short* ga0 = A  + (size_t)(m0 + r0)      * lda + koff;
    const unsigned short* ga1 = A  + (size_t)(m0 + r0 + 64) * lda + koff;
    const unsigned short* gb0 = Bt + (size_t)(n0 + r0)      * ldb + koff;
    const unsigned short* gb1 = Bt + (size_t)(n0 + r0 + 64) * ldb + koff;
    unsigned short* la0 = As + t * 8;
    unsigned short* la1 = As + t * 8 + 2048;
    unsigned short* lb0 = Bs + t * 8;
    unsigned short* lb1 = Bs + t * 8 + 2048;

    f32x4 acc[4][4];
    #pragma unroll
    for (int i = 0; i < 4; ++i)
        #pragma unroll
        for (int j = 0; j < 4; ++j) acc[i][j] = (f32x4)0.0f;

    const int fm = lane & 15;
    const int fq = (lane >> 4) * 8;
    const int arow = (wm * 64 + fm) * 32 + fq;   // + i*512
    const int brow = (wn * 64 + fm) * 32 + fq;   // + j*512

    for (int k0 = 0; k0 < K; k0 += 32) {
        GLDS16(ga0 + k0, la0);
        GLDS16(ga1 + k0, la1);
        GLDS16(gb0 + k0, lb0);
        GLDS16(gb1 + k0, lb1);
        __syncthreads();
        bf16x8 af[4], bg[4];
        #pragma unroll
        for (int i = 0; i < 4; ++i) af[i] = *(const bf16x8*)(As + arow + i * 512);
        #pragma unroll
        for (int j = 0; j < 4; ++j) bg[j] = *(const bf16x8*)(Bs + brow + j * 512);
        #pragma unroll
        for (int i = 0; i < 4; ++i)
            #pragma unroll
            for (int j = 0; j < 4; ++j)
                acc[i][j] = __builtin_amdgcn_mfma_f32_16x16x32_bf16(
                    af[i], bg[j], acc[i][j], 0, 0, 0);
        __syncthreads();
    }

    const int cb  = n0 + wn * 64 + fm;
    const int rbs = m0 + wm * 64 + (lane >> 4) * 4;
    #pragma unroll
    for (int j = 0; j < 4; ++j) {
        const int n = cb + j * 16;
        const float bv = bias[n];
        #pragma unroll
        for (int i = 0; i < 4; ++i) {
            #pragma unroll
            for (int r = 0; r < 4; ++r) {
                float v = acc[i][j][r] + bv;
                if (ACT == 1) v = fmaxf(v, 0.0f);
                if (ACT == 2) v = 0.5f * v * (1.0f + erff(v * 0.7071067811865476f));
                const size_t off = (size_t)(rbs + i * 16 + r) * ldc + n;
                if (OUTM == 2) Cf[off] = v;
                Cb[off] = f2bf(v);
            }
        }
    }
}

// ---------------------------------------------------------------------------
// one-shot weight conversion: transpose to [N][K] bf16 + bias concat
// ---------------------------------------------------------------------------
#define CW_QKV  786432   // 4*768*256
#define CW_O   1048576   // + 4*256*256
#define CW_1   1572864   // + 4*512*256
#define CW_2   2097152   // + 4*256*512
#define CW_X   2129920   // + 256*128
#define CW_B   2132992   // + 4*768
__global__ __launch_bounds__(256) void conv_weights(
    const float* __restrict__ Wq, const float* __restrict__ Wk,
    const float* __restrict__ Wv, const float* __restrict__ Wo,
    const float* __restrict__ fw1, const float* __restrict__ fw2,
    const float* __restrict__ Wx_w,
    const float* __restrict__ bq, const float* __restrict__ bk,
    const float* __restrict__ bv,
    unsigned short* __restrict__ wqkv_t, unsigned short* __restrict__ wo_t,
    unsigned short* __restrict__ w1_t, unsigned short* __restrict__ w2_t,
    unsigned short* __restrict__ wx_bf, float* __restrict__ bqkv)
{
    const int e = blockIdx.x * 256 + threadIdx.x;
    if (e < CW_QKV) {
        const int i = e / 196608, r = e % 196608;
        const int n = r / 256, k = r % 256;
        const float* src = (n < 256) ? Wq : (n < 512) ? Wk : Wv;
        wqkv_t[e] = f2bf(src[((size_t)i * 256 + k) * 256 + (n & 255)]);
    } else if (e < CW_O) {
        const int r = e - CW_QKV;
        const int i = r / 65536, rr = r % 65536, n = rr / 256, k = rr % 256;
        wo_t[r] = f2bf(Wo[((size_t)i * 256 + k) * 256 + n]);
    } else if (e < CW_1) {
        const int r = e - CW_O;
        const int i = r / 131072, rr = r % 131072, n = rr / 256, k = rr % 256;
        w1_t[r] = f2bf(fw1[((size_t)i * 256 + k) * 512 + n]);
    } else if (e < CW_2) {
        const int r = e - CW_1;
        const int i = r / 131072, rr = r % 131072, n = rr / 512, k = rr % 512;
        w2_t[r] = f2bf(fw2[((size_t)i * 512 + k) * 256 + n]);
    } else if (e < CW_X) {
        const int r = e - CW_2;
        wx_bf[r] = f2bf(Wx_w[r]);     // Wx_w [out][in] is already B^T layout
    } else if (e < CW_B) {
        const int r = e - CW_X;
        const int i = r / 768, j = r % 768;
        const float v = (j < 256) ? bq[i * 256 + j]
                      : (j < 512) ? bk[i * 256 + j - 256]
                                  : bv[i * 256 + j - 512];
        bqkv[r] = v;
    }
}

// x [B][CIN][NTOK] f32 -> xbf [MTOT][CIN] bf16 (token-major)
__global__ __launch_bounds__(256) void conv_x(
    const float* __restrict__ x, unsigned short* __restrict__ xbf)
{
    const int e = blockIdx.x * 256 + threadIdx.x;     // e < MTOT*128
    const int m = e >> 7, c = e & 127;
    const int b = (m >= NTOK) ? 1 : 0;
    const int n = m - b * NTOK;
    xbf[e] = f2bf(x[((size_t)b * CIN + c) * NTOK + n]);
}

// ---------------------------------------------------------------------------
// k softmax stats over tokens (per b, channel): online max + sumexp; k bf16
// ---------------------------------------------------------------------------
__global__ __launch_bounds__(256) void ksm_stats(
    const unsigned short* __restrict__ qkv, float* __restrict__ Mk, float* __restrict__ Sk)
{
    const int b = blockIdx.x >> 8;
    const int c = blockIdx.x & 255;
    const unsigned short* base = qkv + (size_t)b * NTOK * 768 + 256 + c;
    float m = -1e30f, s = 0.0f;
    for (int n = threadIdx.x; n < NTOK; n += 256) {
        const float v = bf2f(base[(size_t)n * 768]);
        if (v > m) { s = s * __expf(m - v) + 1.0f; m = v; }
        else       { s += __expf(v - m); }
    }
    __shared__ float sm[256], ss[256];
    sm[threadIdx.x] = m; ss[threadIdx.x] = s;
    __syncthreads();
    for (int off = 128; off; off >>= 1) {
        if (threadIdx.x < off) {
            const float m1 = sm[threadIdx.x], s1 = ss[threadIdx.x];
            const float m2 = sm[threadIdx.x + off], s2 = ss[threadIdx.x + off];
            const float M = fmaxf(m1, m2);
            sm[threadIdx.x] = M;
            ss[threadIdx.x] = s1 * __expf(m1 - M) + s2 * __expf(m2 - M);
        }
        __syncthreads();
    }
    if (threadIdx.x == 0) { Mk[blockIdx.x] = sm[0]; Sk[blockIdx.x] = ss[0]; }
}

// ---------------------------------------------------------------------------
// ctx[b][h][d][e] = sum_n softmaxed_k[n][d] * v[n][e]; k,v bf16 in qkv
// ---------------------------------------------------------------------------
__global__ __launch_bounds__(256) void ctx_kernel(
    const unsigned short* __restrict__ qkv,
    const float* __restrict__ Mk, const float* __restrict__ Sk,
    float* __restrict__ ctx)
{
    const int chunk = blockIdx.x, h = blockIdx.y, b = blockIdx.z;
    const int n0 = chunk * 512;
    const int t = threadIdx.x;
    const int col = t & 31;
    const int d0  = t >> 5;   // 0..7
    __shared__ float ke[32][33], ve[32][33];
    float acc[4] = {0, 0, 0, 0};
    const int gc = h * 32 + col;
    const float Mv   = Mk[b * 256 + gc];
    const float invS = 1.0f / Sk[b * 256 + gc];
    const unsigned short* kb = qkv + (size_t)b * NTOK * 768 + 256;
    const unsigned short* vb = qkv + (size_t)b * NTOK * 768 + 512;

    for (int sub = 0; sub < 16; ++sub) {
        const int nb = n0 + sub * 32;
        __syncthreads();
        #pragma unroll
        for (int e = 0; e < 4; ++e) {
            const int tok = d0 + e * 8;
            const size_t idx = (size_t)(nb + tok) * 768 + gc;
            ke[tok][col] = __expf(bf2f(kb[idx]) - Mv) * invS;
            ve[tok][col] = bf2f(vb[idx]);
        }
        __syncthreads();
        #pragma unroll 8
        for (int tok = 0; tok < 32; ++tok) {
            const float vv = ve[tok][col];
            #pragma unroll
            for (int j = 0; j < 4; ++j)
                acc[j] += ke[tok][d0 + 8 * j] * vv;
        }
    }
    float* cp = ctx + (size_t)(b * 8 + h) * 1024;
    #pragma unroll
    for (int j = 0; j < 4; ++j)
        atomicAdd(&cp[(d0 + 8 * j) * 32 + col], acc[j]);
}

// ---------------------------------------------------------------------------
// fused q-softmax (over dk=32) + o = q_sm * ctx; writes bf16 into qkv k-slot
// ---------------------------------------------------------------------------
__global__ __launch_bounds__(256) void ohead_kernel(
    unsigned short* __restrict__ qkv, const float* __restrict__ ctx)
{
    const int row = blockIdx.x;
    const int b = (row >= NTOK) ? 1 : 0;
    const int t = threadIdx.x;
    const int h = t >> 5, e = t & 31;
    const float qv = bf2f(qkv[(size_t)row * 768 + h * 32 + e]);
    float m = qv;
    #pragma unroll
    for (int off = 16; off; off >>= 1) m = fmaxf(m, __shfl_xor(m, off, 32));
    const float ex = __expf(qv - m);
    float s = ex;
    #pragma unroll
    for (int off = 16; off; off >>= 1) s += __shfl_xor(s, off, 32);
    const float qs = ex / s * 0.17677669529663687f; // 1/sqrt(32)
    const float* cp = ctx + (size_t)(b * 8 + h) * 1024 + e;
    float acc = 0.0f;
    #pragma unroll 8
    for (int d = 0; d < 32; ++d) acc += __shfl(qs, d, 32) * cp[d * 32];
    qkv[(size_t)row * 768 + 256 + t] = f2bf(acc);
}

// ---------------------------------------------------------------------------
// t = LayerNorm(t + add(bf16)); writes t f32 in place (+ optional bf16 copy)
// ---------------------------------------------------------------------------
template<int WB>
__global__ __launch_bounds__(256) void ln_kernel(
    float* __restrict__ t, const unsigned short* __restrict__ add,
    const float* __restrict__ g, const float* __restrict__ bta,
    unsigned short* __restrict__ tbf)
{
    const int row = blockIdx.x;
    const int c = threadIdx.x;
    const int lane = c & 63, wave = c >> 6;
    const size_t off = (size_t)row * 256 + c;
    const float v = t[off] + bf2f(add[off]);
    __shared__ float red[8];
    float s = v;
    #pragma unroll
    for (int o = 32; o; o >>= 1) s += __shfl_xor(s, o, 64);
    if (lane == 0) red[wave] = s;
    __syncthreads();
    const float mu = (red[0] + red[1] + red[2] + red[3]) * (1.0f / 256.0f);
    const float dv = v - mu;
    float s2 = dv * dv;
    #pragma unroll
    for (int o = 32; o; o >>= 1) s2 += __shfl_xor(s2, o, 64);
    if (lane == 0) red[wave + 4] = s2;
    __syncthreads();
    const float var = (red[4] + red[5] + red[6] + red[7]) * (1.0f / 256.0f);
    const float o = dv * rsqrtf(var + 1e-6f) * g[c] + bta[c];
    t[off] = o;
    if (WB) tbf[off] = f2bf(o);
}

// ---------------------------------------------------------------------------
// depthwise 3x3x3 conv + residual, register-resident weights + sliding window.
// grid = (24*24, B), block = 256 (thread = channel). Each block walks the 24
// tokens along d. 27 weights in VGPRs; 9 neighbor columns as 9x3 register
// window; 9 coalesced 1024B loads per d-step. No LDS.
// WB: also write bf16 shadow (skipped on last layer).
// ---------------------------------------------------------------------------
template<int WB>
__global__ __launch_bounds__(256) void posconv_kernel(
    const float* __restrict__ tin, const float* __restrict__ pw,
    const float* __restrict__ pb, float* __restrict__ outp,
    unsigned short* __restrict__ tbfp)
{
    const int hw = blockIdx.x;            // 0..575
    const int b  = blockIdx.y;
    const int hh = hw / 24, ww = hw % 24;
    const int c  = threadIdx.x;

    float w[27];
    #pragma unroll
    for (int k = 0; k < 27; ++k) w[k] = pw[c * 27 + k];
    const float bias = pb[c];

    const float* base = tin + (size_t)b * NTOK * 256 + c;

    // neighbor columns j = (dh+1)*3 + (dw+1); weight index = j*3 + (dz+1)
    const float* colp[9];
    bool colok[9];
    #pragma unroll
    for (int dh = -1; dh <= 1; ++dh)
        #pragma unroll
        for (int dw = -1; dw <= 1; ++dw) {
            const int j = (dh + 1) * 3 + (dw + 1);
            const int h2 = hh + dh, w2 = ww + dw;
            colok[j] = ((unsigned)h2 < 24u) & ((unsigned)w2 < 24u);
            colp[j] = base + (size_t)((h2 * 24 + w2) * 24) * 256;
        }

    float win[9][3];
    #pragma unroll
    for (int j = 0; j < 9; ++j) {
        win[j][0] = 0.0f;                                   // depth -1
        win[j][1] = colok[j] ? colp[j][0] : 0.0f;           // depth 0
    }

    float* ob = outp + ((size_t)b * NTOK + (size_t)hw * 24) * 256 + c;
    unsigned short* tb = WB ? (tbfp + ((size_t)b * NTOK + (size_t)hw * 24) * 256 + c)
                            : (unsigned short*)nullptr;

    for (int d = 0; d < 24; ++d) {
        // load depth d+1
        #pragma unroll
        for (int j = 0; j < 9; ++j)
            win[j][2] = (colok[j] && d < 23) ? colp[j][(d + 1) * 256] : 0.0f;

        float acc = bias + win[4][1];     // residual (center, depth d)
        #pragma unroll
        for (int j = 0; j < 9; ++j) {
            acc += w[j * 3 + 0] * win[j][0];
            acc += w[j * 3 + 1] * win[j][1];
            acc += w[j * 3 + 2] * win[j][2];
        }
        ob[d * 256] = acc;
        if (WB) tb[d * 256] = f2bf(acc);

        #pragma unroll
        for (int j = 0; j < 9; ++j) { win[j][0] = win[j][1]; win[j][1] = win[j][2]; }
    }
}

// ---------------------------------------------------------------------------
// final transpose: t [MTOT][256] f32 -> out [B][256][NTOK] (LDS tiled)
// ---------------------------------------------------------------------------
__global__ __launch_bounds__(256) void tr_out(
    const float* __restrict__ tin, float* __restrict__ outp)
{
    __shared__ float tile[32][33];
    const int m0 = blockIdx.x * 32;
    const int c0 = blockIdx.y * 32;
    const int t = threadIdx.x;
    const int tc = t & 31, tr = t >> 5;     // 8 row-groups
    #pragma unroll
    for (int r = 0; r < 4; ++r)
        tile[tr + r * 8][tc] = tin[(size_t)(m0 + tr + r * 8) * 256 + c0 + tc];
    __syncthreads();
    const int b = (m0 >= NTOK) ? 1 : 0;
    const int n0 = m0 - b * NTOK;
    #pragma unroll
    for (int r = 0; r < 4; ++r)
        outp[((size_t)b * 256 + c0 + tr + r * 8) * NTOK + n0 + tc] = tile[tc][tr + r * 8];
}

// ---------------------------------------------------------------------------
// launch
// ---------------------------------------------------------------------------
extern "C" void kernel_launch(void* const* d_in, const int* in_sizes, int n_in,
                              void* d_out, int out_size, void* d_ws, size_t ws_size,
                              hipStream_t stream)
{
    (void)in_sizes; (void)n_in; (void)out_size; (void)ws_size;
    const float* x     = (const float*)d_in[0];
    const float* Wx_w  = (const float*)d_in[1];
    const float* Wx_b  = (const float*)d_in[2];
    const float* Wq    = (const float*)d_in[3];
    const float* bq    = (const float*)d_in[4];
    const float* Wk    = (const float*)d_in[5];
    const float* bk    = (const float*)d_in[6];
    const float* Wv    = (const float*)d_in[7];
    const float* bv    = (const float*)d_in[8];
    const float* Wo    = (const float*)d_in[9];
    const float* bo    = (const float*)d_in[10];
    const float* ln1_g = (const float*)d_in[11];
    const float* ln1_b = (const float*)d_in[12];
    const float* ln2_g = (const float*)d_in[13];
    const float* ln2_b = (const float*)d_in[14];
    const float* fw1   = (const float*)d_in[15];
    const float* fb1   = (const float*)d_in[16];
    const float* fw2   = (const float*)d_in[17];
    const float* fb2   = (const float*)d_in[18];
    const float* pw    = (const float*)d_in[19];
    const float* pb    = (const float*)d_in[20];
    float* out = (float*)d_out;

    char* p = (char*)d_ws;
    float* tA            = (float*)p;          p += (size_t)MTOT * 256 * 4;
    float* tB            = (float*)p;          p += (size_t)MTOT * 256 * 4;
    unsigned short* tbf  = (unsigned short*)p; p += (size_t)MTOT * 256 * 2;
    unsigned short* qkv  = (unsigned short*)p; p += (size_t)MTOT * 768 * 2;
    unsigned short* hbf  = (unsigned short*)p; p += (size_t)MTOT * 512 * 2;
    unsigned short* ob   = (unsigned short*)p; p += (size_t)MTOT * 256 * 2;
    unsigned short* xbf  = (unsigned short*)p; p += (size_t)MTOT * 128 * 2;
    unsigned short* wqkv_t = (unsigned short*)p; p += (size_t)786432 * 2;
    unsigned short* wo_t   = (unsigned short*)p; p += (size_t)262144 * 2;
    unsigned short* w1_t   = (unsigned short*)p; p += (size_t)524288 * 2;
    unsigned short* w2_t   = (unsigned short*)p; p += (size_t)524288 * 2;
    unsigned short* wx_bf  = (unsigned short*)p; p += (size_t)32768 * 2;
    float* bqkv = (float*)p; p += 3072 * 4;
    float* ctx  = (float*)p; p += 16384 * 4;
    float* Mk   = (float*)p; p += 512 * 4;
    float* Sk   = (float*)p; p += 512 * 4;

    hipLaunchKernelGGL(conv_weights, dim3(8333), dim3(256), 0, stream,
                       Wq, Wk, Wv, Wo, fw1, fw2, Wx_w, bq, bk, bv,
                       wqkv_t, wo_t, w1_t, w2_t, wx_bf, bqkv);
    hipLaunchKernelGGL(conv_x, dim3(13824), dim3(256), 0, stream, x, xbf);

    // input 1x1x1 conv + relu -> tA f32 + tbf bf16
    hipLaunchKernelGGL((gemm_bf16<1, 2>), dim3(216, 2), dim3(256), 0, stream,
                       xbf, CIN, wx_bf, CIN, Wx_b, tA, tbf, 256, CIN);

    for (int i = 0; i < NLAYERS; ++i) {
        float* tin  = (i & 1) ? tB : tA;
        float* tout = (i & 1) ? tA : tB;

        // fused QKV: [M,256] x [256,768]
        hipLaunchKernelGGL((gemm_bf16<0, 1>), dim3(216, 6), dim3(256), 0, stream,
                           tbf, 256, wqkv_t + (size_t)i * 196608, 256,
                           bqkv + i * 768, nullptr, qkv, 768, 256);

        hipLaunchKernelGGL(ksm_stats, dim3(512), dim3(256), 0, stream, qkv, Mk, Sk);
        hipMemsetAsync(ctx, 0, 16384 * sizeof(float), stream);
        hipLaunchKernelGGL(ctx_kernel, dim3(27, NHEAD, BATCH), dim3(256), 0, stream,
                           qkv, Mk, Sk, ctx);
        hipLaunchKernelGGL(ohead_kernel, dim3(MTOT), dim3(256), 0, stream, qkv, ctx);

        // o @ Wo + bo -> ob (A = qkv k-slot, lda 768)
        hipLaunchKernelGGL((gemm_bf16<0, 1>), dim3(216, 2), dim3(256), 0, stream,
                           qkv + 256, 768, wo_t + (size_t)i * 65536, 256,
                           bo + i * 256, nullptr, ob, 256, 256);
        hipLaunchKernelGGL((ln_kernel<1>), dim3(MTOT), dim3(256), 0, stream,
                           tin, ob, ln1_g + i * 256, ln1_b + i * 256, tbf);

        // FFN
        hipLaunchKernelGGL((gemm_bf16<2, 1>), dim3(216, 4), dim3(256), 0, stream,
                           tbf, 256, w1_t + (size_t)i * 131072, 256,
                           fb1 + i * 512, nullptr, hbf, 512, 256);
        hipLaunchKernelGGL((gemm_bf16<0, 1>), dim3(216, 2), dim3(256), 0, stream,
                           hbf, 512, w2_t + (size_t)i * 131072, 512,
                           fb2 + i * 256, nullptr, ob, 256, 512);
        hipLaunchKernelGGL((ln_kernel<0>), dim3(MTOT), dim3(256), 0, stream,
                           tin, ob, ln2_g + i * 256, ln2_b + i * 256, nullptr);

        // depthwise conv + residual -> tout f32 (+ tbf bf16 except last layer)
        if (i < NLAYERS - 1)
            hipLaunchKernelGGL((posconv_kernel<1>), dim3(576, BATCH), dim3(256), 0, stream,
                               tin, pw + (size_t)i * 6912, pb + i * 256, tout, tbf);
        else
            hipLaunchKernelGGL((posconv_kernel<0>), dim3(576, BATCH), dim3(256), 0, stream,
                               tin, pw + (size_t)i * 6912, pb + i * 256, tout, nullptr);
    }

    // layer 3 wrote tA (tin alternation: A,B,A,B -> tout of i=3 is tA)
    hipLaunchKernelGGL(tr_out, dim3(MTOT / 32, 8), dim3(256), 0, stream, tA, out);
}